// Round 11
// baseline (593.925 us; speedup 1.0000x reference)
//
#include <hip/hip_runtime.h>
#include <math.h>

// Problem constants
#define BB    8192
#define NN    512
#define KKN   8
#define HH    1024
#define OUTD  (NN * (2 * KKN + 1))   // 8704

typedef unsigned short ushort_t;
typedef __bf16 bf16x8 __attribute__((ext_vector_type(8)));
typedef float  f32x16 __attribute__((ext_vector_type(16)));
typedef float  f32x4  __attribute__((ext_vector_type(4)));
typedef int    i32x4  __attribute__((ext_vector_type(4)));
typedef float  f32x2v __attribute__((ext_vector_type(2)));

// float -> bf16 round-to-nearest-even
__device__ inline ushort_t f2bf(float f) {
    unsigned int u = __float_as_uint(f);
    unsigned int r = (u + 0x7fffu + ((u >> 16) & 1u)) >> 16;
    return (ushort_t)r;
}
__device__ inline float bf2f(ushort_t u) {
    return __uint_as_float(((unsigned int)u) << 16);
}

// 5-op tanh: 1 - 2/(e^{2x}+1). Saturates correctly for |x| large.
__device__ inline float fast_tanh(float x) {
    float t = __expf(x + x);
    return fmaf(-2.f, __builtin_amdgcn_rcpf(t + 1.f), 1.f);
}

// ---------------------------------------------------------------------------
// conv_v: a0b[b][n] = bf16(v_in[b][n] - 0.5), n in [0,512). v_in rows are 1024.
// ---------------------------------------------------------------------------
__global__ __launch_bounds__(256) void conv_v(
    const float* __restrict__ v_in, ushort_t* __restrict__ a0b)
{
    int t = blockIdx.x * 256 + threadIdx.x;          // 0 .. B*512/2-1
    int e0 = t * 2;
    int b = e0 >> 9;
    int n = e0 & 511;
    const float2 v = *(const float2*)(v_in + (size_t)b * (2 * NN) + n);
    ushort_t* o = a0b + (size_t)b * NN + n;
    o[0] = f2bf(v.x - 0.5f);
    o[1] = f2bf(v.y - 0.5f);
}

// ---------------------------------------------------------------------------
// passive_ld_init: v_out passive half = v_in passive half; ld_out = ld_in.
// (The fused GEMM3 then atomicAdds -log terms into ld_out.)
// ---------------------------------------------------------------------------
__global__ __launch_bounds__(256) void passive_ld_init(
    const float* __restrict__ v_in, const float* __restrict__ ld_in,
    float* __restrict__ v_out, float* __restrict__ ld_out)
{
    const int idx = blockIdx.x * 256 + threadIdx.x;   // BB*256
    const int b = idx >> 8;
    const int j = idx & 255;
    const float2 vp = *(const float2*)(v_in + (size_t)b * (2 * NN) + 2 * j);
    *(float2*)(v_out + (size_t)b * (2 * NN) + 2 * j) = vp;
    if (j == 0) ld_out[b] = ld_in[b];
}

// ---------------------------------------------------------------------------
// transpose_cvt: W (Kd x Nd fp32 row-major) -> WT (Nd x Kd bf16 row-major)
// PERM kept for compatibility (unused now — W3 uses natural order).
// ---------------------------------------------------------------------------
template <bool PERM>
__global__ __launch_bounds__(256) void transpose_cvt(
    const float* __restrict__ W, ushort_t* __restrict__ WT, int Kd, int Nd)
{
    __shared__ float tile[32][33];
    const int bx = blockIdx.x * 32;   // n base
    const int by = blockIdx.y * 32;   // k base
    const int tx = threadIdx.x;       // 0..31
    const int ty = threadIdx.y;       // 0..7
#pragma unroll
    for (int i = 0; i < 32; i += 8)
        tile[ty + i][tx] = W[(size_t)(by + ty + i) * Nd + bx + tx];
    __syncthreads();
#pragma unroll
    for (int i = 0; i < 32; i += 8) {
        int r = bx + ty + i;
        if (PERM) r = (r % 17) * 512 + (r / 17);
        WT[(size_t)r * Kd + by + tx] = f2bf(tile[tx][ty + i]);
    }
}

// ---------------------------------------------------------------------------
// bf16 MFMA GEMM, 32x32x16 shape: C = bf16(tanh(A @ B + bias))  (128x128 tile)
// Kept for GEMM1/GEMM2 (small-N shapes; B fully L2-resident there; proven).
// ---------------------------------------------------------------------------
template <bool PERM_BIAS>
__global__ __launch_bounds__(256) void gemm_bt_tanh(
    const ushort_t* __restrict__ A,
    const ushort_t* __restrict__ BT,
    const float* __restrict__ bias,
    ushort_t* __restrict__ C,
    int N_, int K)
{
    __shared__ __align__(16) ushort_t sA[128 * 32];   // [row][k-chunk swizzled] 8 KB
    __shared__ __align__(16) ushort_t sB[128 * 32];

    const int t    = threadIdx.x;
    const int lane = t & 63;
    const int w    = t >> 6;
    const int wy   = w >> 1;
    const int wx   = w & 1;
    const int l31  = lane & 31;
    const int h    = lane >> 5;       // k-half within fragment

    const int brow = blockIdx.y * 128;
    const int bcol = blockIdx.x * 128;

    f32x16 acc[2][2] = {};

    const int cwb = (t & ~63);       // wave-uniform chunk base

    int rS[2], gS[2];
#pragma unroll
    for (int p = 0; p < 2; ++p) {
        const int c = p * 256 + t;
        rS[p] = c >> 2;
        gS[p] = ((c & 3) - (rS[p] >> 1)) & 3;
    }

    int offA[2][2], offB[2][2];
#pragma unroll
    for (int ks = 0; ks < 2; ++ks)
#pragma unroll
        for (int ti = 0; ti < 2; ++ti) {
            const int rA = wy * 64 + ti * 32 + l31;
            offA[ks][ti] = rA * 32 + ((2 * ks + h + (rA >> 1)) & 3) * 8;
            const int rB = wx * 64 + ti * 32 + l31;
            offB[ks][ti] = rB * 32 + ((2 * ks + h + (rB >> 1)) & 3) * 8;
        }

    for (int k0 = 0; k0 < K; k0 += 32) {
        __syncthreads();
#pragma unroll
        for (int p = 0; p < 2; ++p) {
            const int cb = p * 256 + cwb;
            const ushort_t* ga = A  + (size_t)(brow + rS[p]) * K + k0 + gS[p] * 8;
            const ushort_t* gb = BT + (size_t)(bcol + rS[p]) * K + k0 + gS[p] * 8;
            __builtin_amdgcn_global_load_lds(
                (const __attribute__((address_space(1))) void*)ga,
                (__attribute__((address_space(3))) void*)(sA + (size_t)cb * 8), 16, 0, 0);
            __builtin_amdgcn_global_load_lds(
                (const __attribute__((address_space(1))) void*)gb,
                (__attribute__((address_space(3))) void*)(sB + (size_t)cb * 8), 16, 0, 0);
        }
        __syncthreads();

#pragma unroll
        for (int ks = 0; ks < 2; ++ks) {
            const bf16x8 a0 = *(const bf16x8*)(sA + offA[ks][0]);
            const bf16x8 a1 = *(const bf16x8*)(sA + offA[ks][1]);
            const bf16x8 b0 = *(const bf16x8*)(sB + offB[ks][0]);
            const bf16x8 b1 = *(const bf16x8*)(sB + offB[ks][1]);
            acc[0][0] = __builtin_amdgcn_mfma_f32_32x32x16_bf16(a0, b0, acc[0][0], 0, 0, 0);
            acc[0][1] = __builtin_amdgcn_mfma_f32_32x32x16_bf16(a0, b1, acc[0][1], 0, 0, 0);
            acc[1][0] = __builtin_amdgcn_mfma_f32_32x32x16_bf16(a1, b0, acc[1][0], 0, 0, 0);
            acc[1][1] = __builtin_amdgcn_mfma_f32_32x32x16_bf16(a1, b1, acc[1][1], 0, 0, 0);
        }
    }

#pragma unroll
    for (int tj = 0; tj < 2; ++tj) {
        const int col = bcol + wx * 64 + tj * 32 + l31;
        const int bidx = PERM_BIAS ? ((col & 511) * 17 + (col >> 9)) : col;
        const float bv = bias[bidx];
#pragma unroll
        for (int ti = 0; ti < 2; ++ti) {
            const int rb = brow + wy * 64 + ti * 32 + 4 * h;
#pragma unroll
            for (int reg = 0; reg < 16; ++reg) {
                const int row = rb + (reg & 3) + 8 * (reg >> 2);
                C[(size_t)row * N_ + col] = f2bf(fast_tanh(acc[ti][tj][reg] + bv));
            }
        }
    }
}

// ---------------------------------------------------------------------------
// R16: FUSED GEMM3 + spline. R6-R14 showed 5 structurally different GEMM3
// schedules all land 188-196us (no pipe saturated) -> GEMM3 is at its session
// floor; the remaining lever is DELETING the netc round-trip (139MB write +
// 142MB read) and the spline_post kernel (~45-55us of HBM traffic).
//   Key: in NATURAL W3 order, a unit's 17 spline values are 17 CONTIGUOUS
//   columns (c = n*17 + j). Tile 128 rows x 272 cols = 16 complete units.
//   - 512 thr = 8 waves (2M x 4N). n-tiles 0..15 -> waves as usual (4 each);
//     tile 16 -> wave w computes rows wy*64+wx*16 (reuses aR[wx]) -> all
//     waves do exactly 17 MFMA/slice (balanced).
//   - LDS: staging A 128x32 + B 272x32 (25KB) inside the 128x276-ushort
//     C-stage region (70656 B) -> 2 blocks/CU.
//   - C-stage stride 276 ush (=138 dw = 10 mod 32): lane-quarters (rows +4
//     apart = +8 banks) land on disjoint 8-bank groups -> conflict-free
//     u16 writes, NO XOR swizzle needed.
//   - Spline read from LDS (17 x ds_read_u16 per (row,unit)), v_active from
//     global (coalesced), writes only v_active_out; per-row log-term summed
//     over the 16 lanes of a unit-group (shfl width 16) then ONE atomicAdd
//     into pre-initialized ld_out (device-scope, G12; fp32 reorder ~1e-6).
// ---------------------------------------------------------------------------
__device__ __forceinline__ void stage16(
    const ushort_t* __restrict__ gsrc, ushort_t* lds_dst)
{
    __builtin_amdgcn_global_load_lds(
        (const __attribute__((address_space(1))) void*)gsrc,
        (__attribute__((address_space(3))) void*)lds_dst, 16, 0, 0);
}

#define CSTR 276   // C-stage row stride (ushorts)

__global__ __launch_bounds__(512, 4) void gemm3_spline_fused(
    const ushort_t* __restrict__ A,     // x2b: B x H bf16
    const ushort_t* __restrict__ BT,    // W3T natural: OUTD x H bf16
    const float* __restrict__ bias,     // b3 (natural order)
    const float* __restrict__ v_in,     // B x 2N
    float* __restrict__ v_out,          // B x 2N (passive half pre-filled)
    float* __restrict__ ld_out,         // B (pre-initialized to ld_in)
    int K)                              // = HH
{
    __shared__ __align__(16) ushort_t smem[128 * CSTR];   // 70656 B
    ushort_t* sA = smem;            // 4096 ush (128x32)
    ushort_t* sB = smem + 4096;     // 8704 ush (272x32)

    const int t    = threadIdx.x;
    const int lane = t & 63;
    const int w    = t >> 6;
    const int wy   = w >> 2;        // 0..1  (M half: 64 rows)
    const int wx   = w & 3;         // 0..3
    const int l15  = lane & 15;
    const int kg   = lane >> 4;     // 0..3

    // XCD binding + 2D within-XCD order (R10-verified). gy=64 -> rpx=8.
    const int gx = gridDim.x, gy = gridDim.y;
    int br, bc;
    {
        const int o = blockIdx.y * gx + blockIdx.x;
        if ((gy & 7) == 0) {
            const int rpx = gy >> 3;
            const int xcd = o & 7;
            const int seq = o >> 3;
            const int bpg = rpx << 3;
            const int g   = seq / bpg;
            const int rem = seq % bpg;
            const int gcw = gx - g * 8;
            const int gw  = gcw < 8 ? gcw : 8;
            bc = g * 8 + rem % gw;
            br = xcd * rpx + rem / gw;
        } else {
            const int nwg = gx * gy;
            const int id = (o & 7) * (nwg >> 3) + (o >> 3);
            br = id / gx; bc = id % gx;
        }
    }
    const int brow  = br * 128;
    const int bcol0 = bc * 272;     // W3 column base (natural order)

    f32x4 acc[4][4] = {};
    f32x4 acc2 = {};                // 17th col-tile

    // staging: thread t -> row rT = t>>2, chunk slot t&3, global chunk g8.
    // B rows 256..271 (slots 1024..1087) staged by wave 0 (t<64):
    // rS = 256 + (t>>2); key ((256+r)>>1)&3 == (r>>1)&3 -> same g8.
    const int rT  = t >> 2;
    const int g8  = (((t & 3) ^ ((t >> 3) & 3)) << 3);
    const int wbU = (t & ~63) * 8;
    const size_t rowA  = (size_t)(brow  + rT) * K;
    const size_t rowB0 = (size_t)(bcol0 + rT) * K;
    const size_t rowB1 = (size_t)(bcol0 + 128 + rT) * K;
    const size_t rowB2 = (size_t)(bcol0 + 256 + rT) * K;   // valid for t<64

    // fragment read offsets (swizzled, verified family)
    int offA[4], offB[4], offB2;
#pragma unroll
    for (int m = 0; m < 4; ++m) {
        const int r = wy * 64 + m * 16 + l15;
        offA[m] = r * 32 + (((kg ^ (r >> 1)) & 3) << 3);
    }
#pragma unroll
    for (int n = 0; n < 4; ++n) {
        const int r = wx * 64 + n * 16 + l15;
        offB[n] = r * 32 + (((kg ^ (r >> 1)) & 3) << 3);
    }
    {
        const int r = 256 + l15;
        offB2 = r * 32 + (((kg ^ (r >> 1)) & 3) << 3);
    }

    // m97 cadence, single-buffered; cross-block overlap (2/CU) hides drains.
    for (int k0 = 0; k0 < K; k0 += 32) {
        __syncthreads();
        stage16(A  + rowA  + k0 + g8, sA + wbU);
        stage16(BT + rowB0 + k0 + g8, sB + wbU);
        stage16(BT + rowB1 + k0 + g8, sB + 4096 + wbU);
        if (t < 64) stage16(BT + rowB2 + k0 + g8, sB + 8192);
        __syncthreads();

        bf16x8 aR[4], bR[4];
#pragma unroll
        for (int n = 0; n < 4; ++n) bR[n] = *(const bf16x8*)(sB + offB[n]);
#pragma unroll
        for (int m = 0; m < 4; ++m) aR[m] = *(const bf16x8*)(sA + offA[m]);
        const bf16x8 b2 = *(const bf16x8*)(sB + offB2);
#pragma unroll
        for (int m = 0; m < 4; ++m)
#pragma unroll
            for (int n = 0; n < 4; ++n)
                acc[m][n] = __builtin_amdgcn_mfma_f32_16x16x32_bf16(
                    aR[m], bR[n], acc[m][n], 0, 0, 0);
        acc2 = __builtin_amdgcn_mfma_f32_16x16x32_bf16(aR[wx], b2, acc2, 0, 0, 0);
    }
    __syncthreads();   // last slice's reads done before C-stage overwrite

    // ---- epilogue 1: tanh+bias -> LDS C-stage (stride 276, conflict-free)
    // 16x16 C/D mapping: col=lane&15, row=(lane>>4)*4+reg [m89 verified].
#pragma unroll
    for (int n = 0; n < 4; ++n) {
        const int col = wx * 64 + n * 16 + l15;
        const float bv = bias[bcol0 + col];
#pragma unroll
        for (int m = 0; m < 4; ++m) {
            const int rg0 = wy * 64 + m * 16 + kg * 4;
#pragma unroll
            for (int reg = 0; reg < 4; ++reg)
                smem[(rg0 + reg) * CSTR + col] =
                    f2bf(fast_tanh(acc[m][n][reg] + bv));
        }
    }
    {
        const int col = 256 + l15;
        const float bv = bias[bcol0 + col];
        const int rg0 = wy * 64 + wx * 16 + kg * 4;
#pragma unroll
        for (int reg = 0; reg < 4; ++reg)
            smem[(rg0 + reg) * CSTR + col] =
                f2bf(fast_tanh(acc2[reg] + bv));
    }
    __syncthreads();

    // ---- epilogue 2: spline from LDS. 128 rows x 16 units; thread groups
    // of 16 consecutive lanes share a row (u = t&15).
#pragma unroll 1
    for (int i = 0; i < 4; ++i) {
        const int pair = i * 512 + t;
        const int row  = pair >> 4;         // 0..127
        const int u    = pair & 15;         // 0..15
        const ushort_t* cp = smem + row * CSTR + u * 17;

        float t17[17];
#pragma unroll
        for (int j = 0; j < 17; ++j) t17[j] = bf2f(cp[j]);

        float mx = t17[9];
#pragma unroll
        for (int j = 10; j < 17; ++j) mx = fmaxf(mx, t17[j]);
        float wn[8], wsum = 0.f;
#pragma unroll
        for (int j = 0; j < 8; ++j) { wn[j] = __expf(t17[9 + j] - mx); wsum += wn[j]; }
        const float winv = 1.f / wsum;
#pragma unroll
        for (int j = 0; j < 8; ++j) wn[j] *= winv;

        float eh[9];
#pragma unroll
        for (int j = 0; j < 9; ++j) eh[j] = __expf(t17[j]);
        float denom = 0.f;
#pragma unroll
        for (int k = 0; k < 8; ++k) denom += 0.5f * wn[k] * (eh[k] + eh[k + 1]);
        const float dinv = 1.f / denom;
        float hn[9];
#pragma unroll
        for (int j = 0; j < 9; ++j) hn[j] = eh[j] * dinv;

        float kx[9], ky[9];
        kx[0] = 0.f; ky[0] = 0.f;
#pragma unroll
        for (int k = 0; k < 8; ++k) {
            kx[k + 1] = kx[k] + wn[k];
            ky[k + 1] = ky[k] + 0.5f * wn[k] * (hn[k] + hn[k + 1]);
        }

        const size_t vi = (size_t)(brow + row) * (2 * NN) + NN + bc * 16 + u;
        const float va = v_in[vi];
        int cnt = 0;
#pragma unroll
        for (int j = 0; j < 9; ++j) cnt += (kx[j] < va) ? 1 : 0;
        int k = cnt - 1;
        k = k < 0 ? 0 : (k > KKN - 1 ? KKN - 1 : k);

        const float wseg = wn[k];
        const float hlo = hn[k], hhi = hn[k + 1];
        const float xlo = kx[k], ylo = ky[k];
        const float alpha = (va - xlo) / wseg;
        v_out[vi] = ylo + alpha * hlo * wseg
                  + 0.5f * alpha * alpha * (hhi - hlo) * wseg;
        float lt = __logf(hlo + alpha * (hhi - hlo));

        // sum the 16 unit-terms of this row (lanes t&~15 .. |15)
#pragma unroll
        for (int o = 8; o > 0; o >>= 1) lt += __shfl_xor(lt, o, 16);
        if ((t & 15) == 0)
            atomicAdd(ld_out + brow + row, -lt);
    }
}

// ---------------------------------------------------------------------------
extern "C" void kernel_launch(void* const* d_in, const int* in_sizes, int n_in,
                              void* d_out, int out_size, void* d_ws, size_t ws_size,
                              hipStream_t stream)
{
    const float* v_in = (const float*)d_in[0];   // B x 2N
    const float* ld   = (const float*)d_in[1];   // B x 1
    const float* W1   = (const float*)d_in[2];   // N x H
    const float* b1   = (const float*)d_in[3];   // H
    const float* W2   = (const float*)d_in[4];   // H x H
    const float* b2   = (const float*)d_in[5];   // H
    const float* W3   = (const float*)d_in[6];   // H x OUTD
    const float* b3   = (const float*)d_in[7];   // OUTD

    float* out    = (float*)d_out;
    float* v_out  = out;                           // B*2N
    float* ld_out = out + (size_t)BB * (2 * NN);   // B

    // Flat workspace (no netc needed anymore — spline fused into GEMM3):
    //   [0,8Mi) a0b | [8,24Mi) x1b | [24,40Mi) x2b |
    //   [40,41) W1T | [41,43) W2T | [43,60Mi) W3T
    const size_t Mi = 1048576;
    char* ws = (char*)d_ws;
    ushort_t* a0b = (ushort_t*)(ws);
    ushort_t* x1b = (ushort_t*)(ws + 8 * Mi);
    ushort_t* x2b = (ushort_t*)(ws + 24 * Mi);
    ushort_t* W1T = (ushort_t*)(ws + 40 * Mi);
    ushort_t* W2T = (ushort_t*)(ws + 41 * Mi);
    ushort_t* W3T = (ushort_t*)(ws + 43 * Mi);

    // conversions (W3T natural order now — no PERM)
    conv_v<<<dim3(BB * NN / 2 / 256), dim3(256), 0, stream>>>(v_in, a0b);
    transpose_cvt<false><<<dim3(HH / 32, NN / 32),   dim3(32, 8), 0, stream>>>(W1, W1T, NN, HH);
    transpose_cvt<false><<<dim3(HH / 32, HH / 32),   dim3(32, 8), 0, stream>>>(W2, W2T, HH, HH);
    transpose_cvt<false><<<dim3(OUTD / 32, HH / 32), dim3(32, 8), 0, stream>>>(W3, W3T, HH, OUTD);

    // GEMM1: x1 = tanh((v_passive-0.5) @ W1 + b1)   M=8192 N=1024 K=512
    gemm_bt_tanh<false><<<dim3(HH / 128, BB / 128), dim3(256), 0, stream>>>(
        a0b, W1T, b1, x1b, HH, NN);
    // GEMM2: x2 = tanh(x1 @ W2 + b2)                M=8192 N=1024 K=1024
    gemm_bt_tanh<false><<<dim3(HH / 128, BB / 128), dim3(256), 0, stream>>>(
        x1b, W2T, b2, x2b, HH, HH);

    // passive copy + ld init, then fused GEMM3+spline (single launch)
    passive_ld_init<<<dim3(BB), dim3(256), 0, stream>>>(v_in, ld, v_out, ld_out);
    gemm3_spline_fused<<<dim3(NN / 16, BB / 128), dim3(512), 0, stream>>>(
        x2b, W3T, b3, v_in, v_out, ld_out, HH);
}

// Round 12
// 360.071 us; speedup vs baseline: 1.6495x; 1.6495x over previous
//
#include <hip/hip_runtime.h>
#include <math.h>

// Problem constants
#define BB    8192
#define NN    512
#define KKN   8
#define HH    1024
#define OUTD  (NN * (2 * KKN + 1))   // 8704

typedef unsigned short ushort_t;
typedef __bf16 bf16x8 __attribute__((ext_vector_type(8)));
typedef float  f32x16 __attribute__((ext_vector_type(16)));
typedef float  f32x4  __attribute__((ext_vector_type(4)));
typedef int    i32x4  __attribute__((ext_vector_type(4)));
typedef float  f32x2v __attribute__((ext_vector_type(2)));

// float -> bf16 round-to-nearest-even
__device__ inline ushort_t f2bf(float f) {
    unsigned int u = __float_as_uint(f);
    unsigned int r = (u + 0x7fffu + ((u >> 16) & 1u)) >> 16;
    return (ushort_t)r;
}
__device__ inline float bf2f(ushort_t u) {
    return __uint_as_float(((unsigned int)u) << 16);
}

// 5-op tanh: 1 - 2/(e^{2x}+1). Saturates correctly for |x| large.
__device__ inline float fast_tanh(float x) {
    float t = __expf(x + x);
    return fmaf(-2.f, __builtin_amdgcn_rcpf(t + 1.f), 1.f);
}

// ---------------------------------------------------------------------------
// conv_v: a0b[b][n] = bf16(v_in[b][n] - 0.5), n in [0,512). v_in rows are 1024.
// ---------------------------------------------------------------------------
__global__ __launch_bounds__(256) void conv_v(
    const float* __restrict__ v_in, ushort_t* __restrict__ a0b)
{
    int t = blockIdx.x * 256 + threadIdx.x;          // 0 .. B*512/2-1
    int e0 = t * 2;
    int b = e0 >> 9;
    int n = e0 & 511;
    const float2 v = *(const float2*)(v_in + (size_t)b * (2 * NN) + n);
    ushort_t* o = a0b + (size_t)b * NN + n;
    o[0] = f2bf(v.x - 0.5f);
    o[1] = f2bf(v.y - 0.5f);
}

// ---------------------------------------------------------------------------
// passive_ld_init: v_out passive half = v_in passive half; ld_out = ld_in.
// (The fused GEMM3 then atomicAdds -log terms into ld_out.)
// ---------------------------------------------------------------------------
__global__ __launch_bounds__(256) void passive_ld_init(
    const float* __restrict__ v_in, const float* __restrict__ ld_in,
    float* __restrict__ v_out, float* __restrict__ ld_out)
{
    const int idx = blockIdx.x * 256 + threadIdx.x;   // BB*256
    const int b = idx >> 8;
    const int j = idx & 255;
    const float2 vp = *(const float2*)(v_in + (size_t)b * (2 * NN) + 2 * j);
    *(float2*)(v_out + (size_t)b * (2 * NN) + 2 * j) = vp;
    if (j == 0) ld_out[b] = ld_in[b];
}

// ---------------------------------------------------------------------------
// transpose_cvt: W (Kd x Nd fp32 row-major) -> WT (Nd x Kd bf16 row-major)
// ---------------------------------------------------------------------------
template <bool PERM>
__global__ __launch_bounds__(256) void transpose_cvt(
    const float* __restrict__ W, ushort_t* __restrict__ WT, int Kd, int Nd)
{
    __shared__ float tile[32][33];
    const int bx = blockIdx.x * 32;   // n base
    const int by = blockIdx.y * 32;   // k base
    const int tx = threadIdx.x;       // 0..31
    const int ty = threadIdx.y;       // 0..7
#pragma unroll
    for (int i = 0; i < 32; i += 8)
        tile[ty + i][tx] = W[(size_t)(by + ty + i) * Nd + bx + tx];
    __syncthreads();
#pragma unroll
    for (int i = 0; i < 32; i += 8) {
        int r = bx + ty + i;
        if (PERM) r = (r % 17) * 512 + (r / 17);
        WT[(size_t)r * Kd + by + tx] = f2bf(tile[tx][ty + i]);
    }
}

// ---------------------------------------------------------------------------
// bf16 MFMA GEMM, 32x32x16 shape: C = bf16(tanh(A @ B + bias))  (128x128 tile)
// Kept for GEMM1/GEMM2 (small-N shapes; B fully L2-resident there; proven).
// ---------------------------------------------------------------------------
template <bool PERM_BIAS>
__global__ __launch_bounds__(256) void gemm_bt_tanh(
    const ushort_t* __restrict__ A,
    const ushort_t* __restrict__ BT,
    const float* __restrict__ bias,
    ushort_t* __restrict__ C,
    int N_, int K)
{
    __shared__ __align__(16) ushort_t sA[128 * 32];   // [row][k-chunk swizzled] 8 KB
    __shared__ __align__(16) ushort_t sB[128 * 32];

    const int t    = threadIdx.x;
    const int lane = t & 63;
    const int w    = t >> 6;
    const int wy   = w >> 1;
    const int wx   = w & 1;
    const int l31  = lane & 31;
    const int h    = lane >> 5;       // k-half within fragment

    const int brow = blockIdx.y * 128;
    const int bcol = blockIdx.x * 128;

    f32x16 acc[2][2] = {};

    const int cwb = (t & ~63);       // wave-uniform chunk base

    int rS[2], gS[2];
#pragma unroll
    for (int p = 0; p < 2; ++p) {
        const int c = p * 256 + t;
        rS[p] = c >> 2;
        gS[p] = ((c & 3) - (rS[p] >> 1)) & 3;
    }

    int offA[2][2], offB[2][2];
#pragma unroll
    for (int ks = 0; ks < 2; ++ks)
#pragma unroll
        for (int ti = 0; ti < 2; ++ti) {
            const int rA = wy * 64 + ti * 32 + l31;
            offA[ks][ti] = rA * 32 + ((2 * ks + h + (rA >> 1)) & 3) * 8;
            const int rB = wx * 64 + ti * 32 + l31;
            offB[ks][ti] = rB * 32 + ((2 * ks + h + (rB >> 1)) & 3) * 8;
        }

    for (int k0 = 0; k0 < K; k0 += 32) {
        __syncthreads();
#pragma unroll
        for (int p = 0; p < 2; ++p) {
            const int cb = p * 256 + cwb;
            const ushort_t* ga = A  + (size_t)(brow + rS[p]) * K + k0 + gS[p] * 8;
            const ushort_t* gb = BT + (size_t)(bcol + rS[p]) * K + k0 + gS[p] * 8;
            __builtin_amdgcn_global_load_lds(
                (const __attribute__((address_space(1))) void*)ga,
                (__attribute__((address_space(3))) void*)(sA + (size_t)cb * 8), 16, 0, 0);
            __builtin_amdgcn_global_load_lds(
                (const __attribute__((address_space(1))) void*)gb,
                (__attribute__((address_space(3))) void*)(sB + (size_t)cb * 8), 16, 0, 0);
        }
        __syncthreads();

#pragma unroll
        for (int ks = 0; ks < 2; ++ks) {
            const bf16x8 a0 = *(const bf16x8*)(sA + offA[ks][0]);
            const bf16x8 a1 = *(const bf16x8*)(sA + offA[ks][1]);
            const bf16x8 b0 = *(const bf16x8*)(sB + offB[ks][0]);
            const bf16x8 b1 = *(const bf16x8*)(sB + offB[ks][1]);
            acc[0][0] = __builtin_amdgcn_mfma_f32_32x32x16_bf16(a0, b0, acc[0][0], 0, 0, 0);
            acc[0][1] = __builtin_amdgcn_mfma_f32_32x32x16_bf16(a0, b1, acc[0][1], 0, 0, 0);
            acc[1][0] = __builtin_amdgcn_mfma_f32_32x32x16_bf16(a1, b0, acc[1][0], 0, 0, 0);
            acc[1][1] = __builtin_amdgcn_mfma_f32_32x32x16_bf16(a1, b1, acc[1][1], 0, 0, 0);
        }
    }

#pragma unroll
    for (int tj = 0; tj < 2; ++tj) {
        const int col = bcol + wx * 64 + tj * 32 + l31;
        const int bidx = PERM_BIAS ? ((col & 511) * 17 + (col >> 9)) : col;
        const float bv = bias[bidx];
#pragma unroll
        for (int ti = 0; ti < 2; ++ti) {
            const int rb = brow + wy * 64 + ti * 32 + 4 * h;
#pragma unroll
            for (int reg = 0; reg < 16; ++reg) {
                const int row = rb + (reg & 3) + 8 * (reg >> 2);
                C[(size_t)row * N_ + col] = f2bf(fast_tanh(acc[ti][tj][reg] + bv));
            }
        }
    }
}

// ---------------------------------------------------------------------------
// R17: FUSED GEMM3 + spline, SCRATCH-FREE. R16 post-mortem: WRITE_SIZE 1.2GB
// (ideal 17MB) + MfmaUtil 13.6% = rule #20 violations -> scratch traffic:
//   (1) aR[wx] with runtime wx spilled the fragment array EVERY K-slice
//       (~GBs, inside the GEMM loop);
//   (2) wn[k]/hn[k]/kx[k]/ky[k] with runtime k in the spline epilogue.
// Fixes (everything else byte-identical to R16):
//   (1) dedicated offA2 + one extra ds_read_b128 per slice for the 17th
//       col-tile (same row aR[wx] held; re-read is ~free, register-clean);
//   (2) unrolled compile-time-indexed cndmask select chain for the segment
//       lookup -> all spline arrays stay in registers.
// ---------------------------------------------------------------------------
__device__ __forceinline__ void stage16(
    const ushort_t* __restrict__ gsrc, ushort_t* lds_dst)
{
    __builtin_amdgcn_global_load_lds(
        (const __attribute__((address_space(1))) void*)gsrc,
        (__attribute__((address_space(3))) void*)lds_dst, 16, 0, 0);
}

#define CSTR 276   // C-stage row stride (ushorts)

__global__ __launch_bounds__(512, 4) void gemm3_spline_fused(
    const ushort_t* __restrict__ A,     // x2b: B x H bf16
    const ushort_t* __restrict__ BT,    // W3T natural: OUTD x H bf16
    const float* __restrict__ bias,     // b3 (natural order)
    const float* __restrict__ v_in,     // B x 2N
    float* __restrict__ v_out,          // B x 2N (passive half pre-filled)
    float* __restrict__ ld_out,         // B (pre-initialized to ld_in)
    int K)                              // = HH
{
    __shared__ __align__(16) ushort_t smem[128 * CSTR];   // 70656 B
    ushort_t* sA = smem;            // 4096 ush (128x32)
    ushort_t* sB = smem + 4096;     // 8704 ush (272x32)

    const int t    = threadIdx.x;
    const int lane = t & 63;
    const int w    = t >> 6;
    const int wy   = w >> 2;        // 0..1  (M half: 64 rows)
    const int wx   = w & 3;         // 0..3
    const int l15  = lane & 15;
    const int kg   = lane >> 4;     // 0..3

    // XCD binding + 2D within-XCD order (R10-verified). gy=64 -> rpx=8.
    const int gx = gridDim.x, gy = gridDim.y;
    int br, bc;
    {
        const int o = blockIdx.y * gx + blockIdx.x;
        if ((gy & 7) == 0) {
            const int rpx = gy >> 3;
            const int xcd = o & 7;
            const int seq = o >> 3;
            const int bpg = rpx << 3;
            const int g   = seq / bpg;
            const int rem = seq % bpg;
            const int gcw = gx - g * 8;
            const int gw  = gcw < 8 ? gcw : 8;
            bc = g * 8 + rem % gw;
            br = xcd * rpx + rem / gw;
        } else {
            const int nwg = gx * gy;
            const int id = (o & 7) * (nwg >> 3) + (o >> 3);
            br = id / gx; bc = id % gx;
        }
    }
    const int brow  = br * 128;
    const int bcol0 = bc * 272;     // W3 column base (natural order)

    f32x4 acc[4][4] = {};
    f32x4 acc2 = {};                // 17th col-tile

    // staging: thread t -> row rT = t>>2, chunk slot t&3, global chunk g8.
    const int rT  = t >> 2;
    const int g8  = (((t & 3) ^ ((t >> 3) & 3)) << 3);
    const int wbU = (t & ~63) * 8;
    const size_t rowA  = (size_t)(brow  + rT) * K;
    const size_t rowB0 = (size_t)(bcol0 + rT) * K;
    const size_t rowB1 = (size_t)(bcol0 + 128 + rT) * K;
    const size_t rowB2 = (size_t)(bcol0 + 256 + rT) * K;   // valid for t<64

    // fragment read offsets (swizzled, verified family)
    int offA[4], offB[4], offA2, offB2;
#pragma unroll
    for (int m = 0; m < 4; ++m) {
        const int r = wy * 64 + m * 16 + l15;
        offA[m] = r * 32 + (((kg ^ (r >> 1)) & 3) << 3);
    }
#pragma unroll
    for (int n = 0; n < 4; ++n) {
        const int r = wx * 64 + n * 16 + l15;
        offB[n] = r * 32 + (((kg ^ (r >> 1)) & 3) << 3);
    }
    {
        const int rA2 = wy * 64 + wx * 16 + l15;     // 17th-tile A row
        offA2 = rA2 * 32 + (((kg ^ (rA2 >> 1)) & 3) << 3);
        const int rB2 = 256 + l15;
        offB2 = rB2 * 32 + (((kg ^ (rB2 >> 1)) & 3) << 3);
    }

    // m97 cadence, single-buffered; cross-block overlap (2/CU) hides drains.
    for (int k0 = 0; k0 < K; k0 += 32) {
        __syncthreads();
        stage16(A  + rowA  + k0 + g8, sA + wbU);
        stage16(BT + rowB0 + k0 + g8, sB + wbU);
        stage16(BT + rowB1 + k0 + g8, sB + 4096 + wbU);
        if (t < 64) stage16(BT + rowB2 + k0 + g8, sB + 8192);
        __syncthreads();

        bf16x8 aR[4], bR[4];
#pragma unroll
        for (int n = 0; n < 4; ++n) bR[n] = *(const bf16x8*)(sB + offB[n]);
#pragma unroll
        for (int m = 0; m < 4; ++m) aR[m] = *(const bf16x8*)(sA + offA[m]);
        const bf16x8 a2 = *(const bf16x8*)(sA + offA2);   // no aR[wx]!
        const bf16x8 b2 = *(const bf16x8*)(sB + offB2);
#pragma unroll
        for (int m = 0; m < 4; ++m)
#pragma unroll
            for (int n = 0; n < 4; ++n)
                acc[m][n] = __builtin_amdgcn_mfma_f32_16x16x32_bf16(
                    aR[m], bR[n], acc[m][n], 0, 0, 0);
        acc2 = __builtin_amdgcn_mfma_f32_16x16x32_bf16(a2, b2, acc2, 0, 0, 0);
    }
    __syncthreads();   // last slice's reads done before C-stage overwrite

    // ---- epilogue 1: tanh+bias -> LDS C-stage (stride 276, conflict-free)
    // 16x16 C/D mapping: col=lane&15, row=(lane>>4)*4+reg [m89 verified].
#pragma unroll
    for (int n = 0; n < 4; ++n) {
        const int col = wx * 64 + n * 16 + l15;
        const float bv = bias[bcol0 + col];
#pragma unroll
        for (int m = 0; m < 4; ++m) {
            const int rg0 = wy * 64 + m * 16 + kg * 4;
#pragma unroll
            for (int reg = 0; reg < 4; ++reg)
                smem[(rg0 + reg) * CSTR + col] =
                    f2bf(fast_tanh(acc[m][n][reg] + bv));
        }
    }
    {
        const int col = 256 + l15;
        const float bv = bias[bcol0 + col];
        const int rg0 = wy * 64 + wx * 16 + kg * 4;
#pragma unroll
        for (int reg = 0; reg < 4; ++reg)
            smem[(rg0 + reg) * CSTR + col] =
                f2bf(fast_tanh(acc2[reg] + bv));
    }
    __syncthreads();

    // ---- epilogue 2: spline from LDS. 128 rows x 16 units; thread groups
    // of 16 consecutive lanes share a row (u = t&15). All arrays
    // compile-time-indexed (rule #20): segment lookup = cndmask chain.
#pragma unroll 1
    for (int i = 0; i < 4; ++i) {
        const int pair = i * 512 + t;
        const int row  = pair >> 4;         // 0..127
        const int u    = pair & 15;         // 0..15
        const ushort_t* cp = smem + row * CSTR + u * 17;

        float t17[17];
#pragma unroll
        for (int j = 0; j < 17; ++j) t17[j] = bf2f(cp[j]);

        float mx = t17[9];
#pragma unroll
        for (int j = 10; j < 17; ++j) mx = fmaxf(mx, t17[j]);
        float wn[8], wsum = 0.f;
#pragma unroll
        for (int j = 0; j < 8; ++j) { wn[j] = __expf(t17[9 + j] - mx); wsum += wn[j]; }
        const float winv = 1.f / wsum;
#pragma unroll
        for (int j = 0; j < 8; ++j) wn[j] *= winv;

        float eh[9];
#pragma unroll
        for (int j = 0; j < 9; ++j) eh[j] = __expf(t17[j]);
        float denom = 0.f;
#pragma unroll
        for (int k = 0; k < 8; ++k) denom += 0.5f * wn[k] * (eh[k] + eh[k + 1]);
        const float dinv = 1.f / denom;
        float hn[9];
#pragma unroll
        for (int j = 0; j < 9; ++j) hn[j] = eh[j] * dinv;

        float kx[9], ky[9];
        kx[0] = 0.f; ky[0] = 0.f;
#pragma unroll
        for (int k = 0; k < 8; ++k) {
            kx[k + 1] = kx[k] + wn[k];
            ky[k + 1] = ky[k] + 0.5f * wn[k] * (hn[k] + hn[k + 1]);
        }

        const size_t vi = (size_t)(brow + row) * (2 * NN) + NN + bc * 16 + u;
        const float va = v_in[vi];
        int k = -1;
#pragma unroll
        for (int j = 0; j < 9; ++j) k += (kx[j] < va) ? 1 : 0;
        k = k < 0 ? 0 : (k > KKN - 1 ? KKN - 1 : k);

        // compile-time-indexed select chain (stays in registers)
        float wseg = wn[0], hlo = hn[0], hhi = hn[1], xlo = 0.f, ylo = 0.f;
#pragma unroll
        for (int j = 1; j < 8; ++j) {
            const bool c = (k == j);
            wseg = c ? wn[j]     : wseg;
            hlo  = c ? hn[j]     : hlo;
            hhi  = c ? hn[j + 1] : hhi;
            xlo  = c ? kx[j]     : xlo;
            ylo  = c ? ky[j]     : ylo;
        }

        const float alpha = (va - xlo) / wseg;
        v_out[vi] = ylo + alpha * hlo * wseg
                  + 0.5f * alpha * alpha * (hhi - hlo) * wseg;
        float lt = __logf(hlo + alpha * (hhi - hlo));

        // sum the 16 unit-terms of this row (lanes t&~15 .. |15)
#pragma unroll
        for (int o = 8; o > 0; o >>= 1) lt += __shfl_xor(lt, o, 16);
        if ((t & 15) == 0)
            atomicAdd(ld_out + brow + row, -lt);
    }
}

// ---------------------------------------------------------------------------
extern "C" void kernel_launch(void* const* d_in, const int* in_sizes, int n_in,
                              void* d_out, int out_size, void* d_ws, size_t ws_size,
                              hipStream_t stream)
{
    const float* v_in = (const float*)d_in[0];   // B x 2N
    const float* ld   = (const float*)d_in[1];   // B x 1
    const float* W1   = (const float*)d_in[2];   // N x H
    const float* b1   = (const float*)d_in[3];   // H
    const float* W2   = (const float*)d_in[4];   // H x H
    const float* b2   = (const float*)d_in[5];   // H
    const float* W3   = (const float*)d_in[6];   // H x OUTD
    const float* b3   = (const float*)d_in[7];   // OUTD

    float* out    = (float*)d_out;
    float* v_out  = out;                           // B*2N
    float* ld_out = out + (size_t)BB * (2 * NN);   // B

    // Flat workspace (no netc needed — spline fused into GEMM3):
    //   [0,8Mi) a0b | [8,24Mi) x1b | [24,40Mi) x2b |
    //   [40,41) W1T | [41,43) W2T | [43,60Mi) W3T
    const size_t Mi = 1048576;
    char* ws = (char*)d_ws;
    ushort_t* a0b = (ushort_t*)(ws);
    ushort_t* x1b = (ushort_t*)(ws + 8 * Mi);
    ushort_t* x2b = (ushort_t*)(ws + 24 * Mi);
    ushort_t* W1T = (ushort_t*)(ws + 40 * Mi);
    ushort_t* W2T = (ushort_t*)(ws + 41 * Mi);
    ushort_t* W3T = (ushort_t*)(ws + 43 * Mi);

    // conversions (W3T natural order — no PERM)
    conv_v<<<dim3(BB * NN / 2 / 256), dim3(256), 0, stream>>>(v_in, a0b);
    transpose_cvt<false><<<dim3(HH / 32, NN / 32),   dim3(32, 8), 0, stream>>>(W1, W1T, NN, HH);
    transpose_cvt<false><<<dim3(HH / 32, HH / 32),   dim3(32, 8), 0, stream>>>(W2, W2T, HH, HH);
    transpose_cvt<false><<<dim3(OUTD / 32, HH / 32), dim3(32, 8), 0, stream>>>(W3, W3T, HH, OUTD);

    // GEMM1: x1 = tanh((v_passive-0.5) @ W1 + b1)   M=8192 N=1024 K=512
    gemm_bt_tanh<false><<<dim3(HH / 128, BB / 128), dim3(256), 0, stream>>>(
        a0b, W1T, b1, x1b, HH, NN);
    // GEMM2: x2 = tanh(x1 @ W2 + b2)                M=8192 N=1024 K=1024
    gemm_bt_tanh<false><<<dim3(HH / 128, BB / 128), dim3(256), 0, stream>>>(
        x1b, W2T, b2, x2b, HH, HH);

    // passive copy + ld init, then fused GEMM3+spline (single launch)
    passive_ld_init<<<dim3(BB), dim3(256), 0, stream>>>(v_in, ld, v_out, ld_out);
    gemm3_spline_fused<<<dim3(NN / 16, BB / 128), dim3(512), 0, stream>>>(
        x2b, W3T, b3, v_in, v_out, ld_out, HH);
}